// Round 9
// baseline (97.795 us; speedup 1.0000x reference)
//
#include <hip/hip_runtime.h>

// Problem constants: features [C=32, N], coords [N,3]=(b,h,w),
// output [B=64, C=32, NH=64, NW=256] float32.
#define CC 32
#define BB 64
#define NHH 64
#define NWW 256
#define PLANE (NHH * NWW)        // 16384 cells per batch
#define BSTRIDE (CC * PLANE)     // 524288 floats per batch in out
#define NCELLS (BB * PLANE)      // 1048576 total cells

// ---------- Fallback (round-1) direct scatter ----------
__global__ void pss_scatter_direct(const float* __restrict__ features,
                                   const int* __restrict__ coords,
                                   float* __restrict__ out, int N) {
    int n = blockIdx.x * blockDim.x + threadIdx.x;
    if (n >= N) return;
    int b = coords[3 * n + 0];
    int h = coords[3 * n + 1];
    int w = coords[3 * n + 2];
    int base = b * BSTRIDE + h * NWW + w;
#pragma unroll
    for (int c = 0; c < CC; ++c)
        out[base + c * PLANE] = features[c * N + n];
}

// ---------- K-1: zero invmap ----------
__global__ __launch_bounds__(256) void pss_zero(int4* __restrict__ p, int n4) {
    int i = blockIdx.x * blockDim.x + threadIdx.x;
    if (i < n4) p[i] = make_int4(0, 0, 0, 0);
}

// ---------- K0: invmap scatter (tiny): invmap[cell] = n+1 ----------
__global__ void pss_invmap(const int* __restrict__ coords,
                           int* __restrict__ invmap, int N) {
    int n = blockIdx.x * blockDim.x + threadIdx.x;
    if (n >= N) return;
    int b = coords[3 * n + 0];
    int h = coords[3 * n + 1];
    int w = coords[3 * n + 2];
    invmap[b * PLANE + h * NWW + w] = n + 1;
}

// ---------- K1: wave-private LDS transpose features [C][N] -> featT [N][C] ----
// Each wave owns a 64n x 32c tile in private LDS (stride 66 -> 2-way bank
// aliasing = free). NO __syncthreads anywhere: ds_write -> ds_read within a
// wave is ordered by compiler-inserted lgkmcnt.
//   Loads : 32 independent scalar loads per thread (each instr = 256B
//           contiguous across lanes; all 32 issued -> 8KB/wave in flight).
//   Stores: float4, lanes contiguous (1KB per instr) -> 16 requests/KB,
//           no amplification. Destination sequential in n.
__global__ __launch_bounds__(256) void pss_transpose_wp(
        const float* __restrict__ features, float* __restrict__ featT, int N) {
    __shared__ float lds[4 * CC * 66];  // 4 waves * 32c * (64n + 2 pad) = 33792 B

    int lane = threadIdx.x & 63;
    int wid = threadIdx.x >> 6;
    int n0 = blockIdx.x * 256 + wid * 64;  // wave's base n
    if (n0 >= N) return;                   // whole-wave exit; no barriers in kernel

    float* wl = &lds[wid * CC * 66];

    int n = n0 + lane;
    bool okn = (n < N);

    // Phase 1: 32 independent loads (nontemporal: read-once, keep L3 for featT)
    float f[CC];
#pragma unroll
    for (int c = 0; c < CC; ++c)
        f[c] = okn ? __builtin_nontemporal_load(&features[(size_t)c * N + n])
                   : 0.0f;

    // Phase 2: LDS write c-major; bank = lane%32 -> 2 lanes/bank (free)
#pragma unroll
    for (int c = 0; c < CC; ++c)
        wl[c * 66 + lane] = f[c];

    // Phase 3: transposed read + linear store.
    // store float4 index = n0*8 + lane + 64*j (lanes contiguous, 1KB/instr).
    // lane -> (nl = lane>>3 + 8j, cq = lane&7); reads lds[(4cq+e)*66 + nl]:
    // bank = (8cq + 2e + nl) % 32 -> 2 lanes/bank (free).
    float4* dstv = (float4*)featT;
    int cq = lane & 7;
    int nlb = lane >> 3;
#pragma unroll
    for (int j = 0; j < 8; ++j) {
        int nl = nlb + 8 * j;
        if (n0 + nl < N) {
            float4 v;
            v.x = wl[(4 * cq + 0) * 66 + nl];
            v.y = wl[(4 * cq + 1) * 66 + nl];
            v.z = wl[(4 * cq + 2) * 66 + nl];
            v.w = wl[(4 * cq + 3) * 66 + nl];
            dstv[(size_t)n0 * 8 + lane + 64 * j] = v;
        }
    }
}

// ---------- K2: gather featT rows per cell, emit out coalesced ----------
// featT rows random but L3-resident. out stores nontemporal (write-once
// stream; don't evict featT).
__global__ __launch_bounds__(256) void pss_gather_emit(
        const float* __restrict__ featT, const int* __restrict__ invmap,
        float* __restrict__ out) {
    __shared__ float lds[NWW * (CC + 1)];  // 256 * 33 floats

    int row = blockIdx.x;          // 0 .. B*NH-1  (row = b*NHH + h)
    int b = row / NHH;
    int h = row % NHH;
    int t = threadIdx.x;           // 0..255 = w

    int inv = invmap[(size_t)row * NWW + t];  // coalesced 1KB per block

    if (inv > 0) {
        const float4* src = (const float4*)(featT + (size_t)(inv - 1) * CC);
#pragma unroll
        for (int k = 0; k < CC / 4; ++k) {
            float4 v = src[k];
            lds[t * (CC + 1) + 4 * k + 0] = v.x;
            lds[t * (CC + 1) + 4 * k + 1] = v.y;
            lds[t * (CC + 1) + 4 * k + 2] = v.z;
            lds[t * (CC + 1) + 4 * k + 3] = v.w;
        }
    } else {
#pragma unroll
        for (int k = 0; k < CC; ++k)
            lds[t * (CC + 1) + k] = 0.0f;
    }

    __syncthreads();

    size_t obase = (size_t)b * BSTRIDE + (size_t)h * NWW + t;
#pragma unroll
    for (int c = 0; c < CC; ++c) {
        float v = lds[t * (CC + 1) + c];  // bank (t+c)%32 -> conflict-free
        __builtin_nontemporal_store(v, &out[obase + (size_t)c * PLANE]);
    }
}

extern "C" void kernel_launch(void* const* d_in, const int* in_sizes, int n_in,
                              void* d_out, int out_size, void* d_ws, size_t ws_size,
                              hipStream_t stream) {
    const float* features = (const float*)d_in[0];
    const int* coords = (const int*)d_in[1];
    float* out = (float*)d_out;
    const int N = in_sizes[1] / 3;

    const size_t invmap_bytes = (size_t)NCELLS * sizeof(int);       // 4 MiB
    const size_t featT_bytes = (size_t)N * CC * sizeof(float);      // ~115 MB

    if (ws_size < invmap_bytes + featT_bytes) {
        // Fallback: direct scatter (correct, slower).
        hipMemsetAsync(d_out, 0, (size_t)out_size * sizeof(float), stream);
        int blocks = (N + 255) / 256;
        pss_scatter_direct<<<blocks, 256, 0, stream>>>(features, coords, out, N);
        return;
    }

    int* invmap = (int*)d_ws;
    float* featT = (float*)((char*)d_ws + invmap_bytes);

    // Zero invmap (0 == empty cell).
    pss_zero<<<(NCELLS / 4 + 255) / 256, 256, 0, stream>>>((int4*)invmap,
                                                           NCELLS / 4);

    pss_invmap<<<(N + 255) / 256, 256, 0, stream>>>(coords, invmap, N);

    pss_transpose_wp<<<(N + 255) / 256, 256, 0, stream>>>(features, featT, N);

    pss_gather_emit<<<BB * NHH, 256, 0, stream>>>(featT, invmap, out);
}

// Round 10
// 97.734 us; speedup vs baseline: 1.0006x; 1.0006x over previous
//
#include <hip/hip_runtime.h>

// Problem constants: features [C=32, N], coords [N,3]=(b,h,w),
// output [B=64, C=32, NH=64, NW=256] float32.
#define CC 32
#define BB 64
#define NHH 64
#define NWW 256
#define PLANE (NHH * NWW)        // 16384 cells per batch
#define BSTRIDE (CC * PLANE)     // 524288 floats per batch in out
#define NCELLS (BB * PLANE)      // 1048576 total cells

// ---------- Fallback (round-1) direct scatter ----------
__global__ void pss_scatter_direct(const float* __restrict__ features,
                                   const int* __restrict__ coords,
                                   float* __restrict__ out, int N) {
    int n = blockIdx.x * blockDim.x + threadIdx.x;
    if (n >= N) return;
    int b = coords[3 * n + 0];
    int h = coords[3 * n + 1];
    int w = coords[3 * n + 2];
    int base = b * BSTRIDE + h * NWW + w;
#pragma unroll
    for (int c = 0; c < CC; ++c)
        out[base + c * PLANE] = features[c * N + n];
}

// ---------- K-1: zero invmap ----------
__global__ __launch_bounds__(256) void pss_zero(int4* __restrict__ p, int n4) {
    int i = blockIdx.x * blockDim.x + threadIdx.x;
    if (i < n4) p[i] = make_int4(0, 0, 0, 0);
}

// ---------- K0: invmap scatter (tiny): invmap[cell] = n+1 ----------
__global__ void pss_invmap(const int* __restrict__ coords,
                           int* __restrict__ invmap, int N) {
    int n = blockIdx.x * blockDim.x + threadIdx.x;
    if (n >= N) return;
    int b = coords[3 * n + 0];
    int h = coords[3 * n + 1];
    int w = coords[3 * n + 2];
    invmap[b * PLANE + h * NWW + w] = n + 1;
}

// ---------- K1: wave-private LDS transpose features [C][N] -> featT [N][C] ----
// Each wave owns a 64n x 32c tile in private LDS (stride 66 -> 2-way bank
// aliasing = free). NO __syncthreads anywhere: ds_write -> ds_read within a
// wave is ordered by compiler-inserted lgkmcnt.
//   Loads : 32 independent scalar loads per thread (each instr = 256B
//           contiguous across lanes; all 32 issued -> 8KB/wave in flight).
//   Stores: float4, lanes contiguous (1KB per instr) -> 16 requests/KB,
//           no amplification. Destination sequential in n.
__global__ __launch_bounds__(256) void pss_transpose_wp(
        const float* __restrict__ features, float* __restrict__ featT, int N) {
    __shared__ float lds[4 * CC * 66];  // 4 waves * 32c * (64n + 2 pad) = 33792 B

    int lane = threadIdx.x & 63;
    int wid = threadIdx.x >> 6;
    int n0 = blockIdx.x * 256 + wid * 64;  // wave's base n
    if (n0 >= N) return;                   // whole-wave exit; no barriers in kernel

    float* wl = &lds[wid * CC * 66];

    int n = n0 + lane;
    bool okn = (n < N);

    // Phase 1: 32 independent loads (nontemporal: read-once, keep L3 for featT)
    float f[CC];
#pragma unroll
    for (int c = 0; c < CC; ++c)
        f[c] = okn ? __builtin_nontemporal_load(&features[(size_t)c * N + n])
                   : 0.0f;

    // Phase 2: LDS write c-major; bank = lane%32 -> 2 lanes/bank (free)
#pragma unroll
    for (int c = 0; c < CC; ++c)
        wl[c * 66 + lane] = f[c];

    // Phase 3: transposed read + linear store.
    // store float4 index = n0*8 + lane + 64*j (lanes contiguous, 1KB/instr).
    // lane -> (nl = lane>>3 + 8j, cq = lane&7); reads lds[(4cq+e)*66 + nl]:
    // bank = (8cq + 2e + nl) % 32 -> 2 lanes/bank (free).
    float4* dstv = (float4*)featT;
    int cq = lane & 7;
    int nlb = lane >> 3;
#pragma unroll
    for (int j = 0; j < 8; ++j) {
        int nl = nlb + 8 * j;
        if (n0 + nl < N) {
            float4 v;
            v.x = wl[(4 * cq + 0) * 66 + nl];
            v.y = wl[(4 * cq + 1) * 66 + nl];
            v.z = wl[(4 * cq + 2) * 66 + nl];
            v.w = wl[(4 * cq + 3) * 66 + nl];
            dstv[(size_t)n0 * 8 + lane + 64 * j] = v;
        }
    }
}

// ---------- K2: gather featT rows per cell, emit out coalesced ----------
// featT rows random but L3-resident. out stores nontemporal (write-once
// stream; don't evict featT).
__global__ __launch_bounds__(256) void pss_gather_emit(
        const float* __restrict__ featT, const int* __restrict__ invmap,
        float* __restrict__ out) {
    __shared__ float lds[NWW * (CC + 1)];  // 256 * 33 floats

    int row = blockIdx.x;          // 0 .. B*NH-1  (row = b*NHH + h)
    int b = row / NHH;
    int h = row % NHH;
    int t = threadIdx.x;           // 0..255 = w

    int inv = invmap[(size_t)row * NWW + t];  // coalesced 1KB per block

    if (inv > 0) {
        const float4* src = (const float4*)(featT + (size_t)(inv - 1) * CC);
#pragma unroll
        for (int k = 0; k < CC / 4; ++k) {
            float4 v = src[k];
            lds[t * (CC + 1) + 4 * k + 0] = v.x;
            lds[t * (CC + 1) + 4 * k + 1] = v.y;
            lds[t * (CC + 1) + 4 * k + 2] = v.z;
            lds[t * (CC + 1) + 4 * k + 3] = v.w;
        }
    } else {
#pragma unroll
        for (int k = 0; k < CC; ++k)
            lds[t * (CC + 1) + k] = 0.0f;
    }

    __syncthreads();

    size_t obase = (size_t)b * BSTRIDE + (size_t)h * NWW + t;
#pragma unroll
    for (int c = 0; c < CC; ++c) {
        float v = lds[t * (CC + 1) + c];  // bank (t+c)%32 -> conflict-free
        __builtin_nontemporal_store(v, &out[obase + (size_t)c * PLANE]);
    }
}

extern "C" void kernel_launch(void* const* d_in, const int* in_sizes, int n_in,
                              void* d_out, int out_size, void* d_ws, size_t ws_size,
                              hipStream_t stream) {
    const float* features = (const float*)d_in[0];
    const int* coords = (const int*)d_in[1];
    float* out = (float*)d_out;
    const int N = in_sizes[1] / 3;

    const size_t invmap_bytes = (size_t)NCELLS * sizeof(int);       // 4 MiB
    const size_t featT_bytes = (size_t)N * CC * sizeof(float);      // ~115 MB

    if (ws_size < invmap_bytes + featT_bytes) {
        // Fallback: direct scatter (correct, slower).
        hipMemsetAsync(d_out, 0, (size_t)out_size * sizeof(float), stream);
        int blocks = (N + 255) / 256;
        pss_scatter_direct<<<blocks, 256, 0, stream>>>(features, coords, out, N);
        return;
    }

    int* invmap = (int*)d_ws;
    float* featT = (float*)((char*)d_ws + invmap_bytes);

    // Zero invmap (0 == empty cell).
    pss_zero<<<(NCELLS / 4 + 255) / 256, 256, 0, stream>>>((int4*)invmap,
                                                           NCELLS / 4);

    pss_invmap<<<(N + 255) / 256, 256, 0, stream>>>(coords, invmap, N);

    pss_transpose_wp<<<(N + 255) / 256, 256, 0, stream>>>(features, featT, N);

    pss_gather_emit<<<BB * NHH, 256, 0, stream>>>(featT, invmap, out);
}